// Round 12
// baseline (416.849 us; speedup 1.0000x reference)
//
#include <hip/hip_runtime.h>
#include <hip/hip_bf16.h>

// ---- JAX PRNG variant switches (verified passing in R2) ----
#define JAX_PARTITIONABLE 1
#define PART_MODE 2   // bits = o0 ^ o1

#define HW 4096      // 64*64 pixels
#define NS 12        // num_steps
#define PPB 49152    // HW*NS points per batch element

typedef __attribute__((ext_vector_type(8))) short short8;
typedef __attribute__((ext_vector_type(4))) float f32x4;

__host__ __device__ __forceinline__ void tf2x32(unsigned k0, unsigned k1,
                                                unsigned x0, unsigned x1,
                                                unsigned &o0, unsigned &o1) {
  unsigned ks2 = k0 ^ k1 ^ 0x1BD11BDAu;
  unsigned v0 = x0 + k0, v1 = x1 + k1;
#define TFR(r) do { v0 += v1; v1 = (v1 << (r)) | (v1 >> (32 - (r))); v1 ^= v0; } while (0)
  TFR(13); TFR(15); TFR(26); TFR(6);   v0 += k1;  v1 += ks2 + 1u;
  TFR(17); TFR(29); TFR(16); TFR(24);  v0 += ks2; v1 += k0 + 2u;
  TFR(13); TFR(15); TFR(26); TFR(6);   v0 += k0;  v1 += k1 + 3u;
  TFR(17); TFR(29); TFR(16); TFR(24);  v0 += k1;  v1 += ks2 + 4u;
  TFR(13); TFR(15); TFR(26); TFR(6);   v0 += ks2; v1 += k0 + 5u;
#undef TFR
  o0 = v0; o1 = v1;
}

__device__ __forceinline__ float jax_uniform(unsigned k0, unsigned k1,
                                             unsigned idx, unsigned total) {
  unsigned o0, o1, bits;
#if JAX_PARTITIONABLE
  tf2x32(k0, k1, 0u, idx, o0, o1);
#if PART_MODE == 0
  bits = o0;
#elif PART_MODE == 1
  bits = o1;
#else
  bits = o0 ^ o1;
#endif
#else
  unsigned half = total >> 1;
  if (idx < half) { tf2x32(k0, k1, idx, idx + half, o0, o1); bits = o0; }
  else            { tf2x32(k0, k1, idx - half, idx, o0, o1); bits = o1; }
#endif
  return __uint_as_float(0x3f800000u | (bits >> 9)) - 1.0f;
}

__device__ __forceinline__ void pixel_dir(int n, float &dx, float &dy, float &dz) {
  int pi = n >> 6, pj = n & 63;
  float x = -1.0f + (float)pj * (2.0f / 63.0f);
  float y =  1.0f - (float)pi * (2.0f / 63.0f);
  float zc = -1.0f / tanf(0.10471975511965978f);  // deg2rad(12)/2
  float inv = 1.0f / sqrtf(x * x + y * y + zc * zc);
  dx = x * inv; dy = y * inv; dz = zc * inv;
}

// ---------------- fused front: prep (40 blk) + map (B blk) + rays ------------
// Independent prologue work in ONE launch (block-uniform branch): saves 2
// launches + graph gaps from the serial chain. Bodies identical to R11.
__global__ __launch_bounds__(256) void k_front(const float *hw, const float *ow,
                                               unsigned short *Whi, unsigned short *Wlo,
                                               float *owT,
                                               const float *z,
                                               const float *mw0, const float *mb0,
                                               const float *mw1, const float *mb1,
                                               const float *mw2, const float *mb2,
                                               float *freqs, float *phases,
                                               const float *c2w, float *zv, float *pts,
                                               unsigned kp0, unsigned kp1,
                                               int npts, int B) {
  __shared__ float zl[256], h1[256], h2[256];
  const int blk = blockIdx.x;
  const int t = threadIdx.x;
  if (blk < 40) {
    // ---- weight prep: hi/lo bf16 split in MFMA A-fragment order ----
    int tid = blk * 256 + t;
    if (tid < 10240) {
      int lane = tid & 63;
      int chunk = tid >> 6;          // (L*8+jt)*4+kb, L=0..4
      int kb = chunk & 3;
      int jt = (chunk >> 2) & 7;
      int L = chunk >> 5;
      int m = lane & 15, quad = lane >> 4;
      int j = jt * 16 + m;
      int k0 = kb * 32 + quad * 8;
      size_t off = (size_t)chunk * 512 + lane * 8;
#pragma unroll
      for (int i = 0; i < 8; i++) {
        float wv = hw[((size_t)L * 128 + k0 + i) * 128 + j];
        unsigned u = __float_as_uint(wv);
        Whi[off + i] = (unsigned short)(u >> 16);
        float r = wv - __uint_as_float(u & 0xFFFF0000u);
        Wlo[off + i] = (unsigned short)(__float_as_uint(r) >> 16);
      }
    }
    if (tid < 512) {
      int k = tid >> 2, c = tid & 3;
      owT[c * 128 + k] = ow[k * 4 + c];
    }
  } else if (blk < 40 + B) {
    // ---- mapping network ----
    int b = blk - 40;
    zl[t] = z[b * 256 + t];
    __syncthreads();
    float acc = mb0[t];
    for (int k = 0; k < 256; k++) acc += zl[k] * mw0[k * 256 + t];
    h1[t] = (acc >= 0.0f) ? acc : 0.2f * acc;
    __syncthreads();
    acc = mb1[t];
    for (int k = 0; k < 256; k++) acc += h1[k] * mw1[k * 256 + t];
    h2[t] = (acc >= 0.0f) ? acc : 0.2f * acc;
    __syncthreads();
    float a6[6];
#pragma unroll
    for (int m = 0; m < 6; m++) a6[m] = mb2[t + m * 256];
    for (int k = 0; k < 256; k++) {
      float h = h2[k];
#pragma unroll
      for (int m = 0; m < 6; m++) a6[m] += h * mw2[k * 1536 + t + m * 256];
    }
#pragma unroll
    for (int m = 0; m < 6; m++) {
      int o = t + m * 256;
      if (o < 768) freqs[b * 768 + o] = a6[m] * 15.0f + 30.0f;
      else         phases[b * 768 + (o - 768)] = a6[m];
    }
  } else {
    // ---- coarse rays ----
    int e = (blk - 40 - B) * 256 + t;
    if (e >= npts) return;
    int b = e / PPB, r = e % PPB, n = r / NS, s = r % NS;
    float dx, dy, dz; pixel_dir(n, dx, dy, dz);
    float delta = (1.12f - 0.88f) / 11.0f;
    float u = jax_uniform(kp0, kp1, (unsigned)e, (unsigned)npts);
    float zval = 0.88f + (float)s * delta + (u - 0.5f) * (float)(0.24 / 11.0);
    zv[e] = zval;
    float px = dx * zval, py = dy * zval, pz = dz * zval;
    const float *M = c2w + b * 16;
    float m[12];
#pragma unroll
    for (int i = 0; i < 12; i++) m[i] = M[i];
    pts[e * 3 + 0] = m[0] * px + m[1] * py + m[2] * pz + m[3];
    pts[e * 3 + 1] = m[4] * px + m[5] * py + m[6] * pz + m[7];
    pts[e * 3 + 2] = m[8] * px + m[9] * py + m[10] * pz + m[11];
  }
}

// ---------------- SIREN forward v10: MFMA + prefetch + phase rotation --------
// R11 counters: MfmaUtil 22%, per-wave ~90% stalled, ~2.5K cyc/group — 10x the
// L2-hit latency. Theory: same-line L2 contention (all resident blocks stream
// the identical W-fragment sequence in lockstep; no multicast -> serialized
// slice responses). v10: per-block phase rotation rot=(blockIdx&3)*2 of the
// 8-group sequence decorrelates the streams (4 regions in flight per CU).
// Even rotation keeps kb pairs adjacent so B-conversion still fires at each
// new kb. Accumulation kb-order changes: f32 rounding shift ~1e-6, harmless.
#define INV2PI 0.15915494309189535f

__global__ __launch_bounds__(64, 2) void k_siren(const float *pts, const float *freqs,
                                                 const float *phases,
                                                 const float *fw, const float *fb,
                                                 const unsigned short *Whi,
                                                 const unsigned short *Wlo,
                                                 const float *hb,
                                                 const float *owT, const float *ob,
                                                 float *outp) {
  __shared__ __align__(16) float xl[32 * 128];   // [p][k], 16 KB
  const int lane = threadIdx.x;
  const int col = lane & 15;
  const int quad = lane >> 4;
  const int base = blockIdx.x * 32;
  const int b = base / PPB;
  const int rot = (blockIdx.x & 3) << 1;   // 0,2,4,6
  const float *fqb = freqs + b * 768;
  const float *phb = phases + b * 768;

  // ---- first layer (VALU) ----
  {
    float pt[24];
    const float4 *ps = (const float4 *)(pts + (size_t)(base + 8 * quad) * 3);
#pragma unroll
    for (int i = 0; i < 6; i++) ((float4 *)pt)[i] = ps[i];
    float frv[8], prv[8], w0v[8], w1v[8], w2v[8], biv[8];
#pragma unroll
    for (int u = 0; u < 2; u++) {
      ((float4 *)frv)[u] = ((const float4 *)fqb)[2 * col + u];
      ((float4 *)prv)[u] = ((const float4 *)phb)[2 * col + u];
      ((float4 *)w0v)[u] = ((const float4 *)fw)[2 * col + u];
      ((float4 *)w1v)[u] = ((const float4 *)(fw + 128))[2 * col + u];
      ((float4 *)w2v)[u] = ((const float4 *)(fw + 256))[2 * col + u];
      ((float4 *)biv)[u] = ((const float4 *)fb)[2 * col + u];
    }
#pragma unroll
    for (int u = 0; u < 8; u++) { frv[u] *= INV2PI; prv[u] *= INV2PI; }
#pragma unroll
    for (int p = 0; p < 8; p++) {
      float x = pt[3 * p], y = pt[3 * p + 1], z = pt[3 * p + 2];
      float s[8];
#pragma unroll
      for (int j = 0; j < 8; j++)
        s[j] = __builtin_amdgcn_sinf(frv[j] * (x * w0v[j] + y * w1v[j] + z * w2v[j] + biv[j]) + prv[j]);
      int pp = 8 * quad + p;
      int s4 = (pp & 15) << 2;
      float4 v0, v1;
      v0.x = s[0]; v0.y = s[1]; v0.z = s[2]; v0.w = s[3];
      v1.x = s[4]; v1.y = s[5]; v1.z = s[6]; v1.w = s[7];
      *((float4 *)&xl[pp * 128 + ((8 * col) ^ s4)]) = v0;
      *((float4 *)&xl[pp * 128 + ((8 * col + 4) ^ s4)]) = v1;
    }
  }
  __syncthreads();

  // ---- hidden layers: MFMA, double-buffered prefetch, rotated group order ---
#pragma unroll 1
  for (int L = 1; L < 6; L++) {
    const int L1 = L - 1;
    f32x4 acc[2][8];
#pragma unroll
    for (int jt = 0; jt < 8; jt++) {
      const float4 bi = *((const float4 *)(hb + L1 * 128 + jt * 16 + quad * 4));
      f32x4 bv;
      bv[0] = bi.x; bv[1] = bi.y; bv[2] = bi.z; bv[3] = bi.w;
      acc[0][jt] = bv;
      acc[1][jt] = bv;
    }
    const short8 *WhiV = (const short8 *)Whi + (size_t)L1 * 2048;
    const short8 *WloV = (const short8 *)Wlo + (size_t)L1 * 2048;

    short8 bufh[2][4], bufl[2][4];
    // prefetch first (rotated) group: Ge = rot (even -> half=0)
    {
      const int g0kb = rot >> 1;
#pragma unroll
      for (int j = 0; j < 4; j++) {
        bufh[0][j] = WhiV[((0 * 4 + j) * 4 + g0kb) * 64 + lane];
        bufl[0][j] = WloV[((0 * 4 + j) * 4 + g0kb) * 64 + lane];
      }
    }
    short8 xhi[2], xlo[2];
#pragma unroll
    for (int i = 0; i < 8; i++) {
      const int Ge = (i + rot) & 7;
      const int kb = Ge >> 1, half = Ge & 1;
      const int cur = i & 1, nxt = (i + 1) & 1;
      // issue next group's loads first (stay in flight across this group's work)
      if (i < 7) {
        const int Gn = (i + 1 + rot) & 7;
        const int nkb = Gn >> 1, nh = Gn & 1;
#pragma unroll
        for (int j = 0; j < 4; j++) {
          bufh[nxt][j] = WhiV[((nh * 4 + j) * 4 + nkb) * 64 + lane];
          bufl[nxt][j] = WloV[((nh * 4 + j) * 4 + nkb) * 64 + lane];
        }
      }
      // at each new kb: convert B fragments from LDS (overlaps the loads)
      if (half == 0) {
        const int jq = kb * 32 + quad * 8;
#pragma unroll
        for (int s = 0; s < 2; s++) {
          int p = s * 16 + col;
          int s4 = col << 2;
          const float4 x0 = *((const float4 *)&xl[p * 128 + (jq ^ s4)]);
          const float4 x1 = *((const float4 *)&xl[p * 128 + ((jq + 4) ^ s4)]);
          float v[8] = {x0.x, x0.y, x0.z, x0.w, x1.x, x1.y, x1.z, x1.w};
#pragma unroll
          for (int ii = 0; ii < 8; ii++) {
            unsigned u = __float_as_uint(v[ii]);
            xhi[s][ii] = (short)(u >> 16);
            float r = v[ii] - __uint_as_float(u & 0xFFFF0000u);
            xlo[s][ii] = (short)(__float_as_uint(r) >> 16);
          }
        }
      }
      // MFMAs for jts half*4 .. half*4+3
#pragma unroll
      for (int j = 0; j < 4; j++) {
        const int jt = half * 4 + j;
        short8 ah = bufh[cur][j];
        short8 al = bufl[cur][j];
        acc[0][jt] = __builtin_amdgcn_mfma_f32_16x16x32_bf16(ah, xhi[0], acc[0][jt], 0, 0, 0);
        acc[1][jt] = __builtin_amdgcn_mfma_f32_16x16x32_bf16(ah, xhi[1], acc[1][jt], 0, 0, 0);
        acc[0][jt] = __builtin_amdgcn_mfma_f32_16x16x32_bf16(ah, xlo[0], acc[0][jt], 0, 0, 0);
        acc[1][jt] = __builtin_amdgcn_mfma_f32_16x16x32_bf16(ah, xlo[1], acc[1][jt], 0, 0, 0);
        acc[0][jt] = __builtin_amdgcn_mfma_f32_16x16x32_bf16(al, xhi[0], acc[0][jt], 0, 0, 0);
        acc[1][jt] = __builtin_amdgcn_mfma_f32_16x16x32_bf16(al, xhi[1], acc[1][jt], 0, 0, 0);
      }
    }
    __syncthreads();
    // epilogue: lane holds rows j = jt*16 + quad*4 + reg, cols p = s*16 + col
#pragma unroll
    for (int jt = 0; jt < 8; jt++) {
      const float4 fq = *((const float4 *)(fqb + L * 128 + jt * 16 + quad * 4));
      const float4 ph = *((const float4 *)(phb + L * 128 + jt * 16 + quad * 4));
#pragma unroll
      for (int s = 0; s < 2; s++) {
        float4 v;
        v.x = __builtin_amdgcn_sinf(fq.x * INV2PI * acc[s][jt][0] + ph.x * INV2PI);
        v.y = __builtin_amdgcn_sinf(fq.y * INV2PI * acc[s][jt][1] + ph.y * INV2PI);
        v.z = __builtin_amdgcn_sinf(fq.z * INV2PI * acc[s][jt][2] + ph.z * INV2PI);
        v.w = __builtin_amdgcn_sinf(fq.w * INV2PI * acc[s][jt][3] + ph.w * INV2PI);
        int p = s * 16 + col;
        int s4 = col << 2;
        *((float4 *)&xl[p * 128 + ((jt * 16 + quad * 4) ^ s4)]) = v;
      }
    }
    __syncthreads();
  }

  // ---- output layer (VALU): lane -> (p = lane>>1, channel pair) -------------
  {
    int p = lane >> 1;
    int c2 = (lane & 1) * 2;
    int s4 = (p & 15) << 2;
    float a0 = ob[c2], a1 = ob[c2 + 1];
#pragma unroll 8
    for (int kk = 0; kk < 32; kk++) {
      const float4 xv = *((const float4 *)&xl[p * 128 + ((kk * 4) ^ s4)]);
      const float4 wA = *((const float4 *)(owT + c2 * 128 + kk * 4));
      const float4 wB = *((const float4 *)(owT + (c2 + 1) * 128 + kk * 4));
      a0 += xv.x * wA.x + xv.y * wA.y + xv.z * wA.z + xv.w * wA.w;
      a1 += xv.x * wB.x + xv.y * wB.y + xv.z * wB.z + xv.w * wB.w;
    }
    a0 = 1.0f / (1.0f + __expf(-a0));
    if (c2 == 0) a1 = 1.0f / (1.0f + __expf(-a1));
    float2 vv; vv.x = a0; vv.y = a1;
    *((float2 *)&outp[(size_t)(base + p) * 4 + c2]) = vv;
  }
}

// ---------------- coarse weights -> sample_pdf -> fine points ----------------
__global__ __launch_bounds__(256) void k_pdf(const float *zv, const float *coutb,
                                             const float *c2w, float *fz, float *fpts,
                                             unsigned kq0, unsigned kq1, int nrays) {
  int ray = blockIdx.x * 256 + threadIdx.x;
  if (ray >= nrays) return;
  int b = ray / HW, n = ray % HW;
  float z[12];
#pragma unroll
  for (int s = 0; s < 12; s++) z[s] = zv[ray * 12 + s];
  float w[12]; float T = 1.0f;
#pragma unroll
  for (int s = 0; s < 12; s++) {
    float d = (s < 11) ? z[s + 1] - z[s] : 1e10f;
    float sg = coutb[(ray * 12 + s) * 4 + 3];
    float a = 1.0f - expf(-d * fmaxf(sg, 0.0f));
    w[s] = a * T;
    T *= 1.0f - a + 1e-10f;
  }
  float zmid[11];
#pragma unroll
  for (int i = 0; i < 11; i++) zmid[i] = 0.5f * (z[i] + z[i + 1]);
  float pw[10], sum = 0.0f;
#pragma unroll
  for (int i = 0; i < 10; i++) { pw[i] = w[i + 1] + 1e-5f; sum += pw[i]; }
  float cdf[11]; cdf[0] = 0.0f; float cacc = 0.0f;
#pragma unroll
  for (int i = 0; i < 10; i++) { cacc += pw[i] / sum; cdf[i + 1] = cacc; }

  const float *M = c2w + b * 16;
  float m[12];
#pragma unroll
  for (int i = 0; i < 12; i++) m[i] = M[i];
  float dx, dy, dz; pixel_dir(n, dx, dy, dz);
  float tdx = m[0] * dx + m[1] * dy + m[2] * dz;
  float tdy = m[4] * dx + m[5] * dy + m[6] * dz;
  float tdz = m[8] * dx + m[9] * dy + m[10] * dz;
  float ox = m[3], oy = m[7], oz = m[11];

#pragma unroll
  for (int t = 0; t < 12; t++) {
    float u = jax_uniform(kq0, kq1, (unsigned)(ray * 12 + t), (unsigned)(nrays * 12));
    int ind = 0;
#pragma unroll
    for (int i = 0; i < 11; i++) ind += (cdf[i] <= u) ? 1 : 0;  // searchsorted 'right'
    int below = ind - 1; below = below < 0 ? 0 : (below > 10 ? 10 : below);
    int above = ind > 10 ? 10 : ind;
    float cl = 0.f, ch = 0.f, blo = 0.f, bhi = 0.f;
#pragma unroll
    for (int i = 0; i < 11; i++) {
      if (i == below) { cl = cdf[i]; blo = zmid[i]; }
      if (i == above) { ch = cdf[i]; bhi = zmid[i]; }
    }
    float den = ch - cl; if (den < 1e-8f) den = 1.0f;
    float f = blo + (u - cl) / den * (bhi - blo);
    fz[ray * 12 + t] = f;
    fpts[(ray * 12 + t) * 3 + 0] = ox + tdx * f;
    fpts[(ray * 12 + t) * 3 + 1] = oy + tdy * f;
    fpts[(ray * 12 + t) * 3 + 2] = oz + tdz * f;
  }
}

// ---------------- merge (stable sort by z), final integration ----------------
__global__ __launch_bounds__(64) void k_final(const float *zv, const float *fz,
                                              const float *coutb, const float *foutb,
                                              float *outp, int B) {
  __shared__ float L[120 * 64];   // per-thread column: z[24], sig[24], rgb[3][24]
  __shared__ int inv[24 * 64];
  int t = threadIdx.x;
  int ray = blockIdx.x * 64 + t;
  int b = ray / HW, n = ray % HW;
#define SL(e) L[(e) * 64 + t]
  float zr[24];
#pragma unroll
  for (int s = 0; s < 12; s++) {
    float zfv = fz[ray * 12 + s], zcv = zv[ray * 12 + s];
    zr[s] = zfv; zr[12 + s] = zcv;   // concat order: fine first, then coarse
    SL(s) = zfv; SL(12 + s) = zcv;
    SL(24 + s)      = foutb[(ray * 12 + s) * 4 + 3];
    SL(24 + 12 + s) = coutb[(ray * 12 + s) * 4 + 3];
#pragma unroll
    for (int c = 0; c < 3; c++) {
      SL(48 + c * 24 + s)      = foutb[(ray * 12 + s) * 4 + c];
      SL(48 + c * 24 + 12 + s) = coutb[(ray * 12 + s) * 4 + c];
    }
  }
  // stable ranks (ties broken by original index) == JAX stable argsort
#pragma unroll
  for (int i = 0; i < 24; i++) {
    int rank = 0;
#pragma unroll
    for (int j = 0; j < 24; j++)
      rank += (zr[j] < zr[i] || (zr[j] == zr[i] && j < i)) ? 1 : 0;
    inv[rank * 64 + t] = i;
  }
  float Tacc = 1.0f, r0 = 0.f, r1 = 0.f, r2 = 0.f, df = 0.f;
  int icur = inv[0 * 64 + t];
  float zcur = SL(icur);
  for (int r = 0; r < 24; r++) {
    int inext = 0; float znext = 0.f;
    if (r < 23) { inext = inv[(r + 1) * 64 + t]; znext = SL(inext); }
    float d = (r < 23) ? znext - zcur : 1e10f;
    float sg = SL(24 + icur);
    float a = 1.0f - expf(-d * fmaxf(sg, 0.0f));
    float wt = a * Tacc;
    Tacc *= 1.0f - a + 1e-10f;
    r0 += wt * SL(48 + icur);
    r1 += wt * SL(48 + 24 + icur);
    r2 += wt * SL(48 + 48 + icur);
    df += wt * zcur;
    icur = inext; zcur = znext;
  }
#undef SL
  int pi = n >> 6, pj = n & 63;
  float x = -1.0f + (float)pj * (2.0f / 63.0f);
  float y =  1.0f - (float)pi * (2.0f / 63.0f);
  float zc = -1.0f / tanf(0.10471975511965978f);
  float invn = 1.0f / sqrtf(x * x + y * y + zc * zc);
  float mdz = -zc * invn;  // -rays_d.z (positive)
  outp[(b * 3 + 0) * HW + n] = r0 * 2.0f - 1.0f;
  outp[(b * 3 + 1) * HW + n] = r1 * 2.0f - 1.0f;
  outp[(b * 3 + 2) * HW + n] = r2 * 2.0f - 1.0f;
  outp[B * 3 * HW + ray] = df * mdz;
}

extern "C" void kernel_launch(void *const *d_in, const int *in_sizes, int n_in,
                              void *d_out, int out_size, void *d_ws, size_t ws_size,
                              hipStream_t stream) {
  const float *z   = (const float *)d_in[0];
  const float *c2w = (const float *)d_in[1];
  const float *mw0 = (const float *)d_in[2];
  const float *mb0 = (const float *)d_in[3];
  const float *mw1 = (const float *)d_in[4];
  const float *mb1 = (const float *)d_in[5];
  const float *mw2 = (const float *)d_in[6];
  const float *mb2 = (const float *)d_in[7];
  const float *fw  = (const float *)d_in[8];
  const float *fb  = (const float *)d_in[9];
  const float *hw  = (const float *)d_in[10];
  const float *hb  = (const float *)d_in[11];
  const float *ow  = (const float *)d_in[12];
  const float *ob  = (const float *)d_in[13];
  int B = in_sizes[0] / 256;
  int npts = B * PPB;
  int nrays = B * HW;

  float *ws     = (float *)d_ws;
  float *freqs  = ws;
  float *phases = freqs + (size_t)B * 768;
  float *zv     = phases + (size_t)B * 768;
  float *cpts   = zv + npts;
  float *coutb  = cpts + (size_t)npts * 3;
  float *fzv    = coutb + (size_t)npts * 4;
  float *fpts   = fzv + npts;
  float *foutb  = fpts + (size_t)npts * 3;
  unsigned short *whi = (unsigned short *)(foutb + (size_t)npts * 4);  // 16B-aligned
  unsigned short *wlo = whi + 81920;    // 5*8*4*512
  float *owT = (float *)(wlo + 81920);

  // key(42) = [0,42]; split -> k_pert, k_pdf
  unsigned kp0, kp1, kq0, kq1;
#if JAX_PARTITIONABLE
  { unsigned o0, o1;
    tf2x32(0u, 42u, 0u, 0u, o0, o1); kp0 = o0; kp1 = o1;
    tf2x32(0u, 42u, 0u, 1u, o0, o1); kq0 = o0; kq1 = o1; }
#else
  { unsigned a0, a1, c0, c1;
    tf2x32(0u, 42u, 0u, 2u, a0, a1);
    tf2x32(0u, 42u, 1u, 3u, c0, c1);
    kp0 = a0; kp1 = c0; kq0 = a1; kq1 = c1; }
#endif

  int nfront = 40 + B + (npts + 255) / 256;
  k_front<<<nfront, 256, 0, stream>>>(hw, ow, whi, wlo, owT,
                                      z, mw0, mb0, mw1, mb1, mw2, mb2,
                                      freqs, phases, c2w, zv, cpts,
                                      kp0, kp1, npts, B);
  k_siren<<<npts / 32, 64, 0, stream>>>(cpts, freqs, phases, fw, fb, whi, wlo, hb, owT, ob, coutb);
  k_pdf<<<(nrays + 255) / 256, 256, 0, stream>>>(zv, coutb, c2w, fzv, fpts, kq0, kq1, nrays);
  k_siren<<<npts / 32, 64, 0, stream>>>(fpts, freqs, phases, fw, fb, whi, wlo, hb, owT, ob, foutb);
  k_final<<<nrays / 64, 64, 0, stream>>>(zv, fzv, coutb, foutb, (float *)d_out, B);
}

// Round 13
// 291.068 us; speedup vs baseline: 1.4321x; 1.4321x over previous
//
#include <hip/hip_runtime.h>
#include <hip/hip_bf16.h>

// ---- JAX PRNG variant switches (verified passing in R2) ----
#define JAX_PARTITIONABLE 1
#define PART_MODE 2   // bits = o0 ^ o1

#define HW 4096      // 64*64 pixels
#define NS 12        // num_steps
#define PPB 49152    // HW*NS points per batch element

typedef __attribute__((ext_vector_type(8))) short short8;
typedef __attribute__((ext_vector_type(4))) float f32x4;

__host__ __device__ __forceinline__ void tf2x32(unsigned k0, unsigned k1,
                                                unsigned x0, unsigned x1,
                                                unsigned &o0, unsigned &o1) {
  unsigned ks2 = k0 ^ k1 ^ 0x1BD11BDAu;
  unsigned v0 = x0 + k0, v1 = x1 + k1;
#define TFR(r) do { v0 += v1; v1 = (v1 << (r)) | (v1 >> (32 - (r))); v1 ^= v0; } while (0)
  TFR(13); TFR(15); TFR(26); TFR(6);   v0 += k1;  v1 += ks2 + 1u;
  TFR(17); TFR(29); TFR(16); TFR(24);  v0 += ks2; v1 += k0 + 2u;
  TFR(13); TFR(15); TFR(26); TFR(6);   v0 += k0;  v1 += k1 + 3u;
  TFR(17); TFR(29); TFR(16); TFR(24);  v0 += k1;  v1 += ks2 + 4u;
  TFR(13); TFR(15); TFR(26); TFR(6);   v0 += ks2; v1 += k0 + 5u;
#undef TFR
  o0 = v0; o1 = v1;
}

__device__ __forceinline__ float jax_uniform(unsigned k0, unsigned k1,
                                             unsigned idx, unsigned total) {
  unsigned o0, o1, bits;
#if JAX_PARTITIONABLE
  tf2x32(k0, k1, 0u, idx, o0, o1);
#if PART_MODE == 0
  bits = o0;
#elif PART_MODE == 1
  bits = o1;
#else
  bits = o0 ^ o1;
#endif
#else
  unsigned half = total >> 1;
  if (idx < half) { tf2x32(k0, k1, idx, idx + half, o0, o1); bits = o0; }
  else            { tf2x32(k0, k1, idx - half, idx, o0, o1); bits = o1; }
#endif
  return __uint_as_float(0x3f800000u | (bits >> 9)) - 1.0f;
}

__device__ __forceinline__ void pixel_dir(int n, float &dx, float &dy, float &dz) {
  int pi = n >> 6, pj = n & 63;
  float x = -1.0f + (float)pj * (2.0f / 63.0f);
  float y =  1.0f - (float)pi * (2.0f / 63.0f);
  float zc = -1.0f / tanf(0.10471975511965978f);  // deg2rad(12)/2
  float inv = 1.0f / sqrtf(x * x + y * y + zc * zc);
  dx = x * inv; dy = y * inv; dz = zc * inv;
}

// ---------------- fused front: prep (40 blk) + map (B blk) + rays ------------
// Kept from R12 (saved ~32us of launch/gap overhead). Bodies identical to R11.
__global__ __launch_bounds__(256) void k_front(const float *hw, const float *ow,
                                               unsigned short *Whi, unsigned short *Wlo,
                                               float *owT,
                                               const float *z,
                                               const float *mw0, const float *mb0,
                                               const float *mw1, const float *mb1,
                                               const float *mw2, const float *mb2,
                                               float *freqs, float *phases,
                                               const float *c2w, float *zv, float *pts,
                                               unsigned kp0, unsigned kp1,
                                               int npts, int B) {
  __shared__ float zl[256], h1[256], h2[256];
  const int blk = blockIdx.x;
  const int t = threadIdx.x;
  if (blk < 40) {
    // ---- weight prep: hi/lo bf16 split in MFMA A-fragment order ----
    int tid = blk * 256 + t;
    if (tid < 10240) {
      int lane = tid & 63;
      int chunk = tid >> 6;          // (L*8+jt)*4+kb, L=0..4
      int kb = chunk & 3;
      int jt = (chunk >> 2) & 7;
      int L = chunk >> 5;
      int m = lane & 15, quad = lane >> 4;
      int j = jt * 16 + m;
      int k0 = kb * 32 + quad * 8;
      size_t off = (size_t)chunk * 512 + lane * 8;
#pragma unroll
      for (int i = 0; i < 8; i++) {
        float wv = hw[((size_t)L * 128 + k0 + i) * 128 + j];
        unsigned u = __float_as_uint(wv);
        Whi[off + i] = (unsigned short)(u >> 16);
        float r = wv - __uint_as_float(u & 0xFFFF0000u);
        Wlo[off + i] = (unsigned short)(__float_as_uint(r) >> 16);
      }
    }
    if (tid < 512) {
      int k = tid >> 2, c = tid & 3;
      owT[c * 128 + k] = ow[k * 4 + c];
    }
  } else if (blk < 40 + B) {
    // ---- mapping network ----
    int b = blk - 40;
    zl[t] = z[b * 256 + t];
    __syncthreads();
    float acc = mb0[t];
    for (int k = 0; k < 256; k++) acc += zl[k] * mw0[k * 256 + t];
    h1[t] = (acc >= 0.0f) ? acc : 0.2f * acc;
    __syncthreads();
    acc = mb1[t];
    for (int k = 0; k < 256; k++) acc += h1[k] * mw1[k * 256 + t];
    h2[t] = (acc >= 0.0f) ? acc : 0.2f * acc;
    __syncthreads();
    float a6[6];
#pragma unroll
    for (int m = 0; m < 6; m++) a6[m] = mb2[t + m * 256];
    for (int k = 0; k < 256; k++) {
      float h = h2[k];
#pragma unroll
      for (int m = 0; m < 6; m++) a6[m] += h * mw2[k * 1536 + t + m * 256];
    }
#pragma unroll
    for (int m = 0; m < 6; m++) {
      int o = t + m * 256;
      if (o < 768) freqs[b * 768 + o] = a6[m] * 15.0f + 30.0f;
      else         phases[b * 768 + (o - 768)] = a6[m];
    }
  } else {
    // ---- coarse rays ----
    int e = (blk - 40 - B) * 256 + t;
    if (e >= npts) return;
    int b = e / PPB, r = e % PPB, n = r / NS, s = r % NS;
    float dx, dy, dz; pixel_dir(n, dx, dy, dz);
    float delta = (1.12f - 0.88f) / 11.0f;
    float u = jax_uniform(kp0, kp1, (unsigned)e, (unsigned)npts);
    float zval = 0.88f + (float)s * delta + (u - 0.5f) * (float)(0.24 / 11.0);
    zv[e] = zval;
    float px = dx * zval, py = dy * zval, pz = dz * zval;
    const float *M = c2w + b * 16;
    float m[12];
#pragma unroll
    for (int i = 0; i < 12; i++) m[i] = M[i];
    pts[e * 3 + 0] = m[0] * px + m[1] * py + m[2] * pz + m[3];
    pts[e * 3 + 1] = m[4] * px + m[5] * py + m[6] * pz + m[7];
    pts[e * 3 + 2] = m[8] * px + m[9] * py + m[10] * pz + m[11];
  }
}

// ---------------- SIREN forward v9 (R11 exact): MFMA + static prefetch -------
// REVERT of R12's runtime phase rotation: rot made W-frag offsets runtime-
// variable, the compiler collapsed the double buffer (VGPR 124->104, MfmaUtil
// 22->11, siren 85.6->165us). Lesson (same as R7): this pipeline survives ONLY
// with compile-time-constant offsets. R11 config: 8 static groups/layer,
// 2-deep register double buffer, VGPR 124, 85.6us, MfmaUtil 22%.
#define INV2PI 0.15915494309189535f

__global__ __launch_bounds__(64, 2) void k_siren(const float *pts, const float *freqs,
                                                 const float *phases,
                                                 const float *fw, const float *fb,
                                                 const unsigned short *Whi,
                                                 const unsigned short *Wlo,
                                                 const float *hb,
                                                 const float *owT, const float *ob,
                                                 float *outp) {
  __shared__ __align__(16) float xl[32 * 128];   // [p][k], 16 KB
  const int lane = threadIdx.x;
  const int col = lane & 15;
  const int quad = lane >> 4;
  const int base = blockIdx.x * 32;
  const int b = base / PPB;
  const float *fqb = freqs + b * 768;
  const float *phb = phases + b * 768;

  // ---- first layer (VALU): lane = (col -> dims 8col..8col+7, quad -> pts 8quad..+7)
  {
    float pt[24];
    const float4 *ps = (const float4 *)(pts + (size_t)(base + 8 * quad) * 3);
#pragma unroll
    for (int i = 0; i < 6; i++) ((float4 *)pt)[i] = ps[i];
    float frv[8], prv[8], w0v[8], w1v[8], w2v[8], biv[8];
#pragma unroll
    for (int u = 0; u < 2; u++) {
      ((float4 *)frv)[u] = ((const float4 *)fqb)[2 * col + u];
      ((float4 *)prv)[u] = ((const float4 *)phb)[2 * col + u];
      ((float4 *)w0v)[u] = ((const float4 *)fw)[2 * col + u];
      ((float4 *)w1v)[u] = ((const float4 *)(fw + 128))[2 * col + u];
      ((float4 *)w2v)[u] = ((const float4 *)(fw + 256))[2 * col + u];
      ((float4 *)biv)[u] = ((const float4 *)fb)[2 * col + u];
    }
#pragma unroll
    for (int u = 0; u < 8; u++) { frv[u] *= INV2PI; prv[u] *= INV2PI; }
#pragma unroll
    for (int p = 0; p < 8; p++) {
      float x = pt[3 * p], y = pt[3 * p + 1], z = pt[3 * p + 2];
      float s[8];
#pragma unroll
      for (int j = 0; j < 8; j++)
        s[j] = __builtin_amdgcn_sinf(frv[j] * (x * w0v[j] + y * w1v[j] + z * w2v[j] + biv[j]) + prv[j]);
      int pp = 8 * quad + p;
      int s4 = (pp & 15) << 2;
      float4 v0, v1;
      v0.x = s[0]; v0.y = s[1]; v0.z = s[2]; v0.w = s[3];
      v1.x = s[4]; v1.y = s[5]; v1.z = s[6]; v1.w = s[7];
      *((float4 *)&xl[pp * 128 + ((8 * col) ^ s4)]) = v0;
      *((float4 *)&xl[pp * 128 + ((8 * col + 4) ^ s4)]) = v1;
    }
  }
  __syncthreads();

  // ---- hidden layers: MFMA with double-buffered A-frag prefetch ----
#pragma unroll 1
  for (int L = 1; L < 6; L++) {
    const int L1 = L - 1;
    f32x4 acc[2][8];
#pragma unroll
    for (int jt = 0; jt < 8; jt++) {
      const float4 bi = *((const float4 *)(hb + L1 * 128 + jt * 16 + quad * 4));
      f32x4 bv;
      bv[0] = bi.x; bv[1] = bi.y; bv[2] = bi.z; bv[3] = bi.w;
      acc[0][jt] = bv;
      acc[1][jt] = bv;
    }
    const short8 *WhiV = (const short8 *)Whi + (size_t)L1 * 2048;
    const short8 *WloV = (const short8 *)Wlo + (size_t)L1 * 2048;

    short8 bufh[2][4], bufl[2][4];
    // prefetch group 0 (kb=0, jts 0..3)
#pragma unroll
    for (int j = 0; j < 4; j++) {
      bufh[0][j] = WhiV[(j * 4 + 0) * 64 + lane];
      bufl[0][j] = WloV[(j * 4 + 0) * 64 + lane];
    }
    short8 xhi[2], xlo[2];
#pragma unroll
    for (int G = 0; G < 8; G++) {
      const int kb = G >> 1, half = G & 1;
      const int cur = G & 1, nxt = (G + 1) & 1;
      // issue next group's loads first (stay in flight across this group's work)
      if (G < 7) {
        const int nkb = (G + 1) >> 1, nh = (G + 1) & 1;
#pragma unroll
        for (int j = 0; j < 4; j++) {
          bufh[nxt][j] = WhiV[((nh * 4 + j) * 4 + nkb) * 64 + lane];
          bufl[nxt][j] = WloV[((nh * 4 + j) * 4 + nkb) * 64 + lane];
        }
      }
      // at each new kb: convert B fragments from LDS (overlaps the loads)
      if (half == 0) {
        const int jq = kb * 32 + quad * 8;
#pragma unroll
        for (int s = 0; s < 2; s++) {
          int p = s * 16 + col;
          int s4 = col << 2;
          const float4 x0 = *((const float4 *)&xl[p * 128 + (jq ^ s4)]);
          const float4 x1 = *((const float4 *)&xl[p * 128 + ((jq + 4) ^ s4)]);
          float v[8] = {x0.x, x0.y, x0.z, x0.w, x1.x, x1.y, x1.z, x1.w};
#pragma unroll
          for (int i = 0; i < 8; i++) {
            unsigned u = __float_as_uint(v[i]);
            xhi[s][i] = (short)(u >> 16);
            float r = v[i] - __uint_as_float(u & 0xFFFF0000u);
            xlo[s][i] = (short)(__float_as_uint(r) >> 16);
          }
        }
      }
      // MFMAs for jts half*4 .. half*4+3 (same per-acc order as R10)
#pragma unroll
      for (int j = 0; j < 4; j++) {
        const int jt = half * 4 + j;
        short8 ah = bufh[cur][j];
        short8 al = bufl[cur][j];
        acc[0][jt] = __builtin_amdgcn_mfma_f32_16x16x32_bf16(ah, xhi[0], acc[0][jt], 0, 0, 0);
        acc[1][jt] = __builtin_amdgcn_mfma_f32_16x16x32_bf16(ah, xhi[1], acc[1][jt], 0, 0, 0);
        acc[0][jt] = __builtin_amdgcn_mfma_f32_16x16x32_bf16(ah, xlo[0], acc[0][jt], 0, 0, 0);
        acc[1][jt] = __builtin_amdgcn_mfma_f32_16x16x32_bf16(ah, xlo[1], acc[1][jt], 0, 0, 0);
        acc[0][jt] = __builtin_amdgcn_mfma_f32_16x16x32_bf16(al, xhi[0], acc[0][jt], 0, 0, 0);
        acc[1][jt] = __builtin_amdgcn_mfma_f32_16x16x32_bf16(al, xhi[1], acc[1][jt], 0, 0, 0);
      }
    }
    __syncthreads();
    // epilogue: lane holds rows j = jt*16 + quad*4 + reg, cols p = s*16 + col
#pragma unroll
    for (int jt = 0; jt < 8; jt++) {
      const float4 fq = *((const float4 *)(fqb + L * 128 + jt * 16 + quad * 4));
      const float4 ph = *((const float4 *)(phb + L * 128 + jt * 16 + quad * 4));
#pragma unroll
      for (int s = 0; s < 2; s++) {
        float4 v;
        v.x = __builtin_amdgcn_sinf(fq.x * INV2PI * acc[s][jt][0] + ph.x * INV2PI);
        v.y = __builtin_amdgcn_sinf(fq.y * INV2PI * acc[s][jt][1] + ph.y * INV2PI);
        v.z = __builtin_amdgcn_sinf(fq.z * INV2PI * acc[s][jt][2] + ph.z * INV2PI);
        v.w = __builtin_amdgcn_sinf(fq.w * INV2PI * acc[s][jt][3] + ph.w * INV2PI);
        int p = s * 16 + col;
        int s4 = col << 2;
        *((float4 *)&xl[p * 128 + ((jt * 16 + quad * 4) ^ s4)]) = v;
      }
    }
    __syncthreads();
  }

  // ---- output layer (VALU): lane -> (p = lane>>1, channel pair) -------------
  {
    int p = lane >> 1;
    int c2 = (lane & 1) * 2;
    int s4 = (p & 15) << 2;
    float a0 = ob[c2], a1 = ob[c2 + 1];
#pragma unroll 8
    for (int kk = 0; kk < 32; kk++) {
      const float4 xv = *((const float4 *)&xl[p * 128 + ((kk * 4) ^ s4)]);
      const float4 wA = *((const float4 *)(owT + c2 * 128 + kk * 4));
      const float4 wB = *((const float4 *)(owT + (c2 + 1) * 128 + kk * 4));
      a0 += xv.x * wA.x + xv.y * wA.y + xv.z * wA.z + xv.w * wA.w;
      a1 += xv.x * wB.x + xv.y * wB.y + xv.z * wB.z + xv.w * wB.w;
    }
    a0 = 1.0f / (1.0f + __expf(-a0));
    if (c2 == 0) a1 = 1.0f / (1.0f + __expf(-a1));
    float2 vv; vv.x = a0; vv.y = a1;
    *((float2 *)&outp[(size_t)(base + p) * 4 + c2]) = vv;
  }
}

// ---------------- coarse weights -> sample_pdf -> fine points ----------------
__global__ __launch_bounds__(256) void k_pdf(const float *zv, const float *coutb,
                                             const float *c2w, float *fz, float *fpts,
                                             unsigned kq0, unsigned kq1, int nrays) {
  int ray = blockIdx.x * 256 + threadIdx.x;
  if (ray >= nrays) return;
  int b = ray / HW, n = ray % HW;
  float z[12];
#pragma unroll
  for (int s = 0; s < 12; s++) z[s] = zv[ray * 12 + s];
  float w[12]; float T = 1.0f;
#pragma unroll
  for (int s = 0; s < 12; s++) {
    float d = (s < 11) ? z[s + 1] - z[s] : 1e10f;
    float sg = coutb[(ray * 12 + s) * 4 + 3];
    float a = 1.0f - expf(-d * fmaxf(sg, 0.0f));
    w[s] = a * T;
    T *= 1.0f - a + 1e-10f;
  }
  float zmid[11];
#pragma unroll
  for (int i = 0; i < 11; i++) zmid[i] = 0.5f * (z[i] + z[i + 1]);
  float pw[10], sum = 0.0f;
#pragma unroll
  for (int i = 0; i < 10; i++) { pw[i] = w[i + 1] + 1e-5f; sum += pw[i]; }
  float cdf[11]; cdf[0] = 0.0f; float cacc = 0.0f;
#pragma unroll
  for (int i = 0; i < 10; i++) { cacc += pw[i] / sum; cdf[i + 1] = cacc; }

  const float *M = c2w + b * 16;
  float m[12];
#pragma unroll
  for (int i = 0; i < 12; i++) m[i] = M[i];
  float dx, dy, dz; pixel_dir(n, dx, dy, dz);
  float tdx = m[0] * dx + m[1] * dy + m[2] * dz;
  float tdy = m[4] * dx + m[5] * dy + m[6] * dz;
  float tdz = m[8] * dx + m[9] * dy + m[10] * dz;
  float ox = m[3], oy = m[7], oz = m[11];

#pragma unroll
  for (int t = 0; t < 12; t++) {
    float u = jax_uniform(kq0, kq1, (unsigned)(ray * 12 + t), (unsigned)(nrays * 12));
    int ind = 0;
#pragma unroll
    for (int i = 0; i < 11; i++) ind += (cdf[i] <= u) ? 1 : 0;  // searchsorted 'right'
    int below = ind - 1; below = below < 0 ? 0 : (below > 10 ? 10 : below);
    int above = ind > 10 ? 10 : ind;
    float cl = 0.f, ch = 0.f, blo = 0.f, bhi = 0.f;
#pragma unroll
    for (int i = 0; i < 11; i++) {
      if (i == below) { cl = cdf[i]; blo = zmid[i]; }
      if (i == above) { ch = cdf[i]; bhi = zmid[i]; }
    }
    float den = ch - cl; if (den < 1e-8f) den = 1.0f;
    float f = blo + (u - cl) / den * (bhi - blo);
    fz[ray * 12 + t] = f;
    fpts[(ray * 12 + t) * 3 + 0] = ox + tdx * f;
    fpts[(ray * 12 + t) * 3 + 1] = oy + tdy * f;
    fpts[(ray * 12 + t) * 3 + 2] = oz + tdz * f;
  }
}

// ---------------- merge (stable sort by z), final integration ----------------
__global__ __launch_bounds__(64) void k_final(const float *zv, const float *fz,
                                              const float *coutb, const float *foutb,
                                              float *outp, int B) {
  __shared__ float L[120 * 64];   // per-thread column: z[24], sig[24], rgb[3][24]
  __shared__ int inv[24 * 64];
  int t = threadIdx.x;
  int ray = blockIdx.x * 64 + t;
  int b = ray / HW, n = ray % HW;
#define SL(e) L[(e) * 64 + t]
  float zr[24];
#pragma unroll
  for (int s = 0; s < 12; s++) {
    float zfv = fz[ray * 12 + s], zcv = zv[ray * 12 + s];
    zr[s] = zfv; zr[12 + s] = zcv;   // concat order: fine first, then coarse
    SL(s) = zfv; SL(12 + s) = zcv;
    SL(24 + s)      = foutb[(ray * 12 + s) * 4 + 3];
    SL(24 + 12 + s) = coutb[(ray * 12 + s) * 4 + 3];
#pragma unroll
    for (int c = 0; c < 3; c++) {
      SL(48 + c * 24 + s)      = foutb[(ray * 12 + s) * 4 + c];
      SL(48 + c * 24 + 12 + s) = coutb[(ray * 12 + s) * 4 + c];
    }
  }
  // stable ranks (ties broken by original index) == JAX stable argsort
#pragma unroll
  for (int i = 0; i < 24; i++) {
    int rank = 0;
#pragma unroll
    for (int j = 0; j < 24; j++)
      rank += (zr[j] < zr[i] || (zr[j] == zr[i] && j < i)) ? 1 : 0;
    inv[rank * 64 + t] = i;
  }
  float Tacc = 1.0f, r0 = 0.f, r1 = 0.f, r2 = 0.f, df = 0.f;
  int icur = inv[0 * 64 + t];
  float zcur = SL(icur);
  for (int r = 0; r < 24; r++) {
    int inext = 0; float znext = 0.f;
    if (r < 23) { inext = inv[(r + 1) * 64 + t]; znext = SL(inext); }
    float d = (r < 23) ? znext - zcur : 1e10f;
    float sg = SL(24 + icur);
    float a = 1.0f - expf(-d * fmaxf(sg, 0.0f));
    float wt = a * Tacc;
    Tacc *= 1.0f - a + 1e-10f;
    r0 += wt * SL(48 + icur);
    r1 += wt * SL(48 + 24 + icur);
    r2 += wt * SL(48 + 48 + icur);
    df += wt * zcur;
    icur = inext; zcur = znext;
  }
#undef SL
  int pi = n >> 6, pj = n & 63;
  float x = -1.0f + (float)pj * (2.0f / 63.0f);
  float y =  1.0f - (float)pi * (2.0f / 63.0f);
  float zc = -1.0f / tanf(0.10471975511965978f);
  float invn = 1.0f / sqrtf(x * x + y * y + zc * zc);
  float mdz = -zc * invn;  // -rays_d.z (positive)
  outp[(b * 3 + 0) * HW + n] = r0 * 2.0f - 1.0f;
  outp[(b * 3 + 1) * HW + n] = r1 * 2.0f - 1.0f;
  outp[(b * 3 + 2) * HW + n] = r2 * 2.0f - 1.0f;
  outp[B * 3 * HW + ray] = df * mdz;
}

extern "C" void kernel_launch(void *const *d_in, const int *in_sizes, int n_in,
                              void *d_out, int out_size, void *d_ws, size_t ws_size,
                              hipStream_t stream) {
  const float *z   = (const float *)d_in[0];
  const float *c2w = (const float *)d_in[1];
  const float *mw0 = (const float *)d_in[2];
  const float *mb0 = (const float *)d_in[3];
  const float *mw1 = (const float *)d_in[4];
  const float *mb1 = (const float *)d_in[5];
  const float *mw2 = (const float *)d_in[6];
  const float *mb2 = (const float *)d_in[7];
  const float *fw  = (const float *)d_in[8];
  const float *fb  = (const float *)d_in[9];
  const float *hw  = (const float *)d_in[10];
  const float *hb  = (const float *)d_in[11];
  const float *ow  = (const float *)d_in[12];
  const float *ob  = (const float *)d_in[13];
  int B = in_sizes[0] / 256;
  int npts = B * PPB;
  int nrays = B * HW;

  float *ws     = (float *)d_ws;
  float *freqs  = ws;
  float *phases = freqs + (size_t)B * 768;
  float *zv     = phases + (size_t)B * 768;
  float *cpts   = zv + npts;
  float *coutb  = cpts + (size_t)npts * 3;
  float *fzv    = coutb + (size_t)npts * 4;
  float *fpts   = fzv + npts;
  float *foutb  = fpts + (size_t)npts * 3;
  unsigned short *whi = (unsigned short *)(foutb + (size_t)npts * 4);  // 16B-aligned
  unsigned short *wlo = whi + 81920;    // 5*8*4*512
  float *owT = (float *)(wlo + 81920);

  // key(42) = [0,42]; split -> k_pert, k_pdf
  unsigned kp0, kp1, kq0, kq1;
#if JAX_PARTITIONABLE
  { unsigned o0, o1;
    tf2x32(0u, 42u, 0u, 0u, o0, o1); kp0 = o0; kp1 = o1;
    tf2x32(0u, 42u, 0u, 1u, o0, o1); kq0 = o0; kq1 = o1; }
#else
  { unsigned a0, a1, c0, c1;
    tf2x32(0u, 42u, 0u, 2u, a0, a1);
    tf2x32(0u, 42u, 1u, 3u, c0, c1);
    kp0 = a0; kp1 = c0; kq0 = a1; kq1 = c1; }
#endif

  int nfront = 40 + B + (npts + 255) / 256;
  k_front<<<nfront, 256, 0, stream>>>(hw, ow, whi, wlo, owT,
                                      z, mw0, mb0, mw1, mb1, mw2, mb2,
                                      freqs, phases, c2w, zv, cpts,
                                      kp0, kp1, npts, B);
  k_siren<<<npts / 32, 64, 0, stream>>>(cpts, freqs, phases, fw, fb, whi, wlo, hb, owT, ob, coutb);
  k_pdf<<<(nrays + 255) / 256, 256, 0, stream>>>(zv, coutb, c2w, fzv, fpts, kq0, kq1, nrays);
  k_siren<<<npts / 32, 64, 0, stream>>>(fpts, freqs, phases, fw, fb, whi, wlo, hb, owT, ob, foutb);
  k_final<<<nrays / 64, 64, 0, stream>>>(zv, fzv, coutb, foutb, (float *)d_out, B);
}